// Round 3
// baseline (347.549 us; speedup 1.0000x reference)
//
#include <hip/hip_runtime.h>
#include <math.h>

#define VOCAB 50000
#define DW 300
#define DH 50
#define G4 200
#define BATCH 1024
#define TMAX 200
#define OUTC 4

// ---------------------------------------------------------------------------
// Kernel 0: transpose + gate-permute w_ih [200][300] -> w_T [300][200] with
// columns u2 = (u%50)*4 + u/50 (unit-major, gate-minor).
__global__ __launch_bounds__(256) void transpose_wih(
    const float* __restrict__ w_ih, float* __restrict__ w_T)
{
    int i = blockIdx.x * 256 + threadIdx.x;
    if (i < G4 * DW) {
        int u = i / DW, k = i % DW;
        int u2 = (u % DH) * 4 + (u / DH);
        w_T[k * G4 + u2] = w_ih[i];
    }
}

// ---------------------------------------------------------------------------
// Kernel A: emb_proj[v][u2] = sum_k emb[v][k]*w_ih[u][k] + b_ih[u] + b_hh[u]
// (unchanged from round 2)
__global__ __launch_bounds__(256, 2) void proj_kernel(
    const float* __restrict__ emb, const float* __restrict__ w_T,
    const float* __restrict__ b_ih, const float* __restrict__ b_hh,
    float* __restrict__ emb_proj)
{
    __shared__ __align__(16) float e_s[100 * 108];  // rows padded to 108 dwords
    const int tid = threadIdx.x;
    const int v0 = blockIdx.x * 100;
    const int m_idx = tid / 25;   // 0..9 (valid for tid<250)
    const int n_idx = tid % 25;   // 0..24

    float acc[10][8];
#pragma unroll
    for (int m = 0; m < 10; m++)
#pragma unroll
        for (int c = 0; c < 8; c++) acc[m][c] = 0.f;

    const float* wcol = w_T + n_idx * 8;

    for (int kc = 0; kc < DW; kc += 100) {
        __syncthreads();   // protect previous chunk reads
        for (int i = tid; i < 2500; i += 256) {
            int r = i / 25, c = i % 25;
            float4 v = *(const float4*)&emb[(size_t)(v0 + r) * DW + kc + c * 4];
            *(float4*)&e_s[r * 108 + c * 4] = v;
        }
        __syncthreads();

        if (tid < 250) {
            float4 wa[4], wb[4];
#pragma unroll
            for (int j = 0; j < 4; j++) {
                const float* p = wcol + (size_t)(kc + j) * G4;
                wa[j] = *(const float4*)p;
                wb[j] = *(const float4*)(p + 4);
            }
            for (int kk = 0; kk < 25; kk++) {
                float4 na[4], nb[4];
                int kn = kc + ((kk < 24) ? (kk + 1) : kk) * 4;
#pragma unroll
                for (int j = 0; j < 4; j++) {
                    const float* p = wcol + (size_t)(kn + j) * G4;
                    na[j] = *(const float4*)p;
                    nb[j] = *(const float4*)(p + 4);
                }
                float4 e4[10];
#pragma unroll
                for (int m = 0; m < 10; m++)
                    e4[m] = *(const float4*)&e_s[(m_idx * 10 + m) * 108 + kk * 4];
#pragma unroll
                for (int j = 0; j < 4; j++) {
#pragma unroll
                    for (int m = 0; m < 10; m++) {
                        float ev = (j == 0) ? e4[m].x : (j == 1) ? e4[m].y
                                 : (j == 2) ? e4[m].z : e4[m].w;
                        acc[m][0] = fmaf(ev, wa[j].x, acc[m][0]);
                        acc[m][1] = fmaf(ev, wa[j].y, acc[m][1]);
                        acc[m][2] = fmaf(ev, wa[j].z, acc[m][2]);
                        acc[m][3] = fmaf(ev, wa[j].w, acc[m][3]);
                        acc[m][4] = fmaf(ev, wb[j].x, acc[m][4]);
                        acc[m][5] = fmaf(ev, wb[j].y, acc[m][5]);
                        acc[m][6] = fmaf(ev, wb[j].z, acc[m][6]);
                        acc[m][7] = fmaf(ev, wb[j].w, acc[m][7]);
                    }
                }
#pragma unroll
                for (int j = 0; j < 4; j++) { wa[j] = na[j]; wb[j] = nb[j]; }
            }
        }
    }

    if (tid < 250) {
        float bias[8];
#pragma unroll
        for (int c = 0; c < 8; c++) {
            int u2 = n_idx * 8 + c;
            int u  = (u2 & 3) * DH + (u2 >> 2);   // inverse gate permutation
            bias[c] = b_ih[u] + b_hh[u];
        }
#pragma unroll
        for (int m = 0; m < 10; m++) {
            float* dst = &emb_proj[(size_t)(v0 + m_idx * 10 + m) * G4 + n_idx * 8];
            *(float4*)dst = make_float4(acc[m][0] + bias[0], acc[m][1] + bias[1],
                                        acc[m][2] + bias[2], acc[m][3] + bias[3]);
            *(float4*)(dst + 4) = make_float4(acc[m][4] + bias[4], acc[m][5] + bias[5],
                                              acc[m][6] + bias[6], acc[m][7] + bias[7]);
        }
    }
}

// ---------------------------------------------------------------------------
// Kernel B (restructured): 256 threads (4 waves) per batch element.
// Thread tid owns ONE gate-row: gate = tid&3, unit = tid>>2 — i.e. output
// column u2 = tid in the gate-permuted layout, so the emb_proj gather is one
// coalesced scalar float per lane. Per-thread weights = 50 floats held in
// NAMED float4/float2 variables (no arrays -> nothing can be demoted to
// scratch; rounds 1-2 proved arrays go to scratch -> 204 KB/CU/step of L2
// reloads = the 1630 cyc/step wall). h broadcast from LDS (same-address
// reads, conflict-free); gates i/f/g/o of a unit live on a lane QUAD and are
// combined with 4 quad_perm DPP broadcasts; c kept redundantly per-quad.
// One barrier per step, h double-buffered.
template <int CTRL>
__device__ __forceinline__ float qbcast(float x) {
    return __int_as_float(__builtin_amdgcn_update_dpp(
        0, __float_as_int(x), CTRL, 0xF, 0xF, true));
}

__global__ __launch_bounds__(256, 2) void lstm_kernel(
    const int* __restrict__ x, const int* __restrict__ lengs,
    const float* __restrict__ emb_proj, const float* __restrict__ w_hh,
    const float* __restrict__ w_out, const float* __restrict__ b_out,
    float* __restrict__ out)
{
    __shared__ __align__(16) float hbuf[2][52];
    __shared__ int x_s[TMAX];
    __shared__ float red[OUTC];

    const int tid  = threadIdx.x;
    const int b    = blockIdx.x;
    const int gate = tid & 3;
    const int unit = tid >> 2;                    // 0..63 (50..63 spare)
    const int uu   = (unit < DH) ? unit : DH - 1; // clamp for safe loads
    const int col  = (tid < G4) ? tid : 0;        // gather column
    const int len  = lengs[b];

    for (int i = tid; i < TMAX; i += 256) x_s[i] = x[b * TMAX + i];
    if (tid < 52) hbuf[0][tid] = 0.f;

    // w_hh row (gate, uu): 50 floats -> 13 NAMED register variables.
    // Rows are 200B-strided (8B aligned) => build float4s from float2 loads.
    const float* wr = w_hh + (size_t)(gate * DH + uu) * DH;
#define LDW(J) ({ float2 ta_ = *(const float2*)(wr + 4 * (J));                \
                  float2 tb_ = *(const float2*)(wr + 4 * (J) + 2);            \
                  make_float4(ta_.x, ta_.y, tb_.x, tb_.y); })
    const float4 W0 = LDW(0),  W1 = LDW(1),  W2  = LDW(2),  W3  = LDW(3);
    const float4 W4 = LDW(4),  W5 = LDW(5),  W6  = LDW(6),  W7  = LDW(7);
    const float4 W8 = LDW(8),  W9 = LDW(9),  W10 = LDW(10), W11 = LDW(11);
    const float2 W12 = *(const float2*)(wr + 48);
#undef LDW

    __syncthreads();   // x_s, hbuf[0] visible

    const float* ep = emb_proj;
    float p0 = ep[(size_t)x_s[0] * G4 + col];
    float p1 = ep[(size_t)x_s[1] * G4 + col];
    float p2 = ep[(size_t)x_s[2] * G4 + col];
    float c_reg = 0.f;

    for (int t = 0; t < len; t++) {
        float cur = p0; p0 = p1; p1 = p2;
        int nt = t + 3; nt = (nt < TMAX) ? nt : TMAX - 1;
        p2 = ep[(size_t)x_s[nt] * G4 + col];

        const float* hb = hbuf[t & 1];
        float4 h0  = *(const float4*)(hb + 0);
        float4 h1  = *(const float4*)(hb + 4);
        float4 h2  = *(const float4*)(hb + 8);
        float4 h3  = *(const float4*)(hb + 12);
        float4 h4  = *(const float4*)(hb + 16);
        float4 h5  = *(const float4*)(hb + 20);
        float4 h6  = *(const float4*)(hb + 24);
        float4 h7  = *(const float4*)(hb + 28);
        float4 h8  = *(const float4*)(hb + 32);
        float4 h9  = *(const float4*)(hb + 36);
        float4 h10 = *(const float4*)(hb + 40);
        float4 h11 = *(const float4*)(hb + 44);
        float2 h12 = *(const float2*)(hb + 48);

#define DOT4(A, H, W)                                                         \
        A = fmaf((H).x, (W).x, fmaf((H).y, (W).y,                             \
            fmaf((H).z, (W).z, fmaf((H).w, (W).w, A))));
        // 4 independent chains, depth 3-4
        float a0 = cur, a1 = 0.f, a2 = 0.f, a3 = 0.f;
        DOT4(a0, h0, W0)  DOT4(a1, h1, W1)  DOT4(a2, h2,  W2)  DOT4(a3, h3,  W3)
        DOT4(a0, h4, W4)  DOT4(a1, h5, W5)  DOT4(a2, h6,  W6)  DOT4(a3, h7,  W7)
        DOT4(a0, h8, W8)  DOT4(a1, h9, W9)  DOT4(a2, h10, W10) DOT4(a3, h11, W11)
        a1 = fmaf(h12.x, W12.x, fmaf(h12.y, W12.y, a1));
#undef DOT4
        float g = (a0 + a1) + (a2 + a3);

        // lane activation: gates 0,1,3 -> sigmoid(g); gate 2 -> tanh(g)
        const bool isg = (gate == 2);
        float arg = isg ? (-2.f * g) : (-g);
        float r   = 1.f / (1.f + __expf(arg));
        float v   = isg ? fmaf(2.f, r, -1.f) : r;

        // combine the quad: lanes 4u..4u+3 hold i,f,g,o of unit u
        float si = qbcast<0x00>(v);
        float sf = qbcast<0x55>(v);
        float tc = qbcast<0xAA>(v);
        float so = qbcast<0xFF>(v);

        float cn = fmaf(sf, c_reg, si * tc);
        c_reg = cn;                         // identical across the quad
        float th = fmaf(2.f, 1.f / (1.f + __expf(-2.f * cn)), -1.f);
        float hn = so * th;
        if ((gate == 0) && (tid < G4)) hbuf[(t + 1) & 1][unit] = hn;
        __syncthreads();
    }

    // logits + softmax (threads 0-3, all in wave 0: LDS ops program-ordered)
    const float* hf = hbuf[len & 1];
    if (tid < OUTC) {
        float lg = b_out[tid];
        const float* wo = w_out + tid * DH;
#pragma unroll
        for (int k = 0; k < DH; k++) lg = fmaf(hf[k], wo[k], lg);
        red[tid] = lg;
    }
    if (tid < OUTC) {
        float m = fmaxf(fmaxf(red[0], red[1]), fmaxf(red[2], red[3]));
        float s = 0.f;
#pragma unroll
        for (int j = 0; j < OUTC; j++) s += __expf(red[j] - m);
        out[b * OUTC + tid] = __expf(red[tid] - m) / s;
    }
}

// ---------------------------------------------------------------------------
extern "C" void kernel_launch(void* const* d_in, const int* in_sizes, int n_in,
                              void* d_out, int out_size, void* d_ws, size_t ws_size,
                              hipStream_t stream) {
    const int*   x     = (const int*)d_in[0];
    const int*   lengs = (const int*)d_in[1];
    const float* emb   = (const float*)d_in[2];
    const float* w_ih  = (const float*)d_in[3];
    const float* w_hh  = (const float*)d_in[4];
    const float* b_ih  = (const float*)d_in[5];
    const float* b_hh  = (const float*)d_in[6];
    const float* w_out = (const float*)d_in[7];
    const float* b_out = (const float*)d_in[8];
    float* out = (float*)d_out;

    float* emb_proj = (float*)d_ws;                       // 40 MB
    float* w_T      = emb_proj + (size_t)VOCAB * G4;      // +240 KB

    hipLaunchKernelGGL(transpose_wih, dim3((G4 * DW + 255) / 256), dim3(256),
                       0, stream, w_ih, w_T);
    hipLaunchKernelGGL(proj_kernel, dim3(VOCAB / 100), dim3(256), 0, stream,
                       emb, w_T, b_ih, b_hh, emb_proj);
    hipLaunchKernelGGL(lstm_kernel, dim3(BATCH), dim3(256), 0, stream,
                       x, lengs, emb_proj, w_hh, w_out, b_out, out);
}

// Round 4
// 325.737 us; speedup vs baseline: 1.0670x; 1.0670x over previous
//
#include <hip/hip_runtime.h>
#include <math.h>

#define VOCAB 50000
#define DW 300
#define DH 50
#define G4 200
#define BATCH 1024
#define TMAX 200
#define OUTC 4

// ---------------------------------------------------------------------------
// Kernel 0: transpose + gate-permute w_ih [200][300] -> w_T [300][200] with
// columns u2 = (u%50)*4 + u/50 (unit-major, gate-minor).
__global__ __launch_bounds__(256) void transpose_wih(
    const float* __restrict__ w_ih, float* __restrict__ w_T)
{
    int i = blockIdx.x * 256 + threadIdx.x;
    if (i < G4 * DW) {
        int u = i / DW, k = i % DW;
        int u2 = (u % DH) * 4 + (u / DH);
        w_T[k * G4 + u2] = w_ih[i];
    }
}

// ---------------------------------------------------------------------------
// Kernel A: emb_proj[v][u2] = sum_k emb[v][k]*w_ih[u][k] + b_ih[u] + b_hh[u]
// (unchanged — isolation; tune with its own counters next round)
__global__ __launch_bounds__(256, 2) void proj_kernel(
    const float* __restrict__ emb, const float* __restrict__ w_T,
    const float* __restrict__ b_ih, const float* __restrict__ b_hh,
    float* __restrict__ emb_proj)
{
    __shared__ __align__(16) float e_s[100 * 108];  // rows padded to 108 dwords
    const int tid = threadIdx.x;
    const int v0 = blockIdx.x * 100;
    const int m_idx = tid / 25;   // 0..9 (valid for tid<250)
    const int n_idx = tid % 25;   // 0..24

    float acc[10][8];
#pragma unroll
    for (int m = 0; m < 10; m++)
#pragma unroll
        for (int c = 0; c < 8; c++) acc[m][c] = 0.f;

    const float* wcol = w_T + n_idx * 8;

    for (int kc = 0; kc < DW; kc += 100) {
        __syncthreads();   // protect previous chunk reads
        for (int i = tid; i < 2500; i += 256) {
            int r = i / 25, c = i % 25;
            float4 v = *(const float4*)&emb[(size_t)(v0 + r) * DW + kc + c * 4];
            *(float4*)&e_s[r * 108 + c * 4] = v;
        }
        __syncthreads();

        if (tid < 250) {
            float4 wa[4], wb[4];
#pragma unroll
            for (int j = 0; j < 4; j++) {
                const float* p = wcol + (size_t)(kc + j) * G4;
                wa[j] = *(const float4*)p;
                wb[j] = *(const float4*)(p + 4);
            }
            for (int kk = 0; kk < 25; kk++) {
                float4 na[4], nb[4];
                int kn = kc + ((kk < 24) ? (kk + 1) : kk) * 4;
#pragma unroll
                for (int j = 0; j < 4; j++) {
                    const float* p = wcol + (size_t)(kn + j) * G4;
                    na[j] = *(const float4*)p;
                    nb[j] = *(const float4*)(p + 4);
                }
                float4 e4[10];
#pragma unroll
                for (int m = 0; m < 10; m++)
                    e4[m] = *(const float4*)&e_s[(m_idx * 10 + m) * 108 + kk * 4];
#pragma unroll
                for (int j = 0; j < 4; j++) {
#pragma unroll
                    for (int m = 0; m < 10; m++) {
                        float ev = (j == 0) ? e4[m].x : (j == 1) ? e4[m].y
                                 : (j == 2) ? e4[m].z : e4[m].w;
                        acc[m][0] = fmaf(ev, wa[j].x, acc[m][0]);
                        acc[m][1] = fmaf(ev, wa[j].y, acc[m][1]);
                        acc[m][2] = fmaf(ev, wa[j].z, acc[m][2]);
                        acc[m][3] = fmaf(ev, wa[j].w, acc[m][3]);
                        acc[m][4] = fmaf(ev, wb[j].x, acc[m][4]);
                        acc[m][5] = fmaf(ev, wb[j].y, acc[m][5]);
                        acc[m][6] = fmaf(ev, wb[j].z, acc[m][6]);
                        acc[m][7] = fmaf(ev, wb[j].w, acc[m][7]);
                    }
                }
#pragma unroll
                for (int j = 0; j < 4; j++) { wa[j] = na[j]; wb[j] = nb[j]; }
            }
        }
    }

    if (tid < 250) {
        float bias[8];
#pragma unroll
        for (int c = 0; c < 8; c++) {
            int u2 = n_idx * 8 + c;
            int u  = (u2 & 3) * DH + (u2 >> 2);   // inverse gate permutation
            bias[c] = b_ih[u] + b_hh[u];
        }
#pragma unroll
        for (int m = 0; m < 10; m++) {
            float* dst = &emb_proj[(size_t)(v0 + m_idx * 10 + m) * G4 + n_idx * 8];
            *(float4*)dst = make_float4(acc[m][0] + bias[0], acc[m][1] + bias[1],
                                        acc[m][2] + bias[2], acc[m][3] + bias[3]);
            *(float4*)(dst + 4) = make_float4(acc[m][4] + bias[4], acc[m][5] + bias[5],
                                              acc[m][6] + bias[6], acc[m][7] + bias[7]);
        }
    }
}

// ---------------------------------------------------------------------------
// Kernel B: back to the round-0 structure — ONE 64-lane wave per batch
// element, lane l owns unit l and ALL FOUR of its w_hh gate rows (200 floats)
// in registers. No barriers (single-wave program order). The NEW piece:
// __attribute__((amdgpu_waves_per_eu(1,1))) caps the occupancy TARGET at
// 1 wave/SIMD, giving the allocator the full 512-reg unified file.
// (__launch_bounds__' 2nd arg is only a FLOOR on waves/EU = ceiling on regs;
// rounds 0-3 proved the scheduler chases max occupancy and spills W to
// scratch -> ~100 KB/CU/step of L1/L2 reloads = the 1630-2160 cyc/step wall
// at VGPR_Count 140/68/44. Budget here: 208 W + ~40 misc < 512.)
__device__ __forceinline__ float tanh_f(float x) {
    float e2 = __expf(fminf(2.f * x, 60.f));
    return (e2 - 1.f) / (e2 + 1.f);
}

__global__ __launch_bounds__(64)
__attribute__((amdgpu_waves_per_eu(1, 1)))
void lstm_kernel(
    const int* __restrict__ x, const int* __restrict__ lengs,
    const float* __restrict__ emb_proj, const float* __restrict__ w_hh,
    const float* __restrict__ w_out, const float* __restrict__ b_out,
    float* __restrict__ out)
{
    __shared__ __align__(16) float h_s[52];
    __shared__ int x_s[TMAX];
    __shared__ float red[OUTC];

    const int l  = threadIdx.x;
    const int b  = blockIdx.x;
    const int ll = (l < DH) ? l : DH - 1;       // lanes 50-63: harmless dup
    const int len = lengs[b];

    for (int i = l; i < TMAX; i += 64) x_s[i] = x[b * TMAX + i];
    if (l < 52) h_s[l] = 0.f;

    // w_hh rows for gates i,f,g,o of unit ll -> registers (float2: 8B aligned)
    float4 rwi[13], rwf[13], rwg[13], rwo[13];
    {
        const float* wr;
#define LOADROW(dst, gate)                                                    \
        wr = w_hh + (size_t)((gate) * DH + ll) * DH;                          \
        _Pragma("unroll")                                                     \
        for (int k4 = 0; k4 < 12; k4++) {                                     \
            float2 a = *(const float2*)(wr + 4 * k4);                         \
            float2 bb = *(const float2*)(wr + 4 * k4 + 2);                    \
            dst[k4] = make_float4(a.x, a.y, bb.x, bb.y);                      \
        }                                                                     \
        { float2 a = *(const float2*)(wr + 48);                               \
          dst[12] = make_float4(a.x, a.y, 0.f, 0.f); }
        LOADROW(rwi, 0) LOADROW(rwf, 1) LOADROW(rwg, 2) LOADROW(rwo, 3)
#undef LOADROW
    }

    float c_reg = 0.f;
    const float* ep = emb_proj;
    float4 p0 = *(const float4*)(ep + (size_t)x_s[0] * G4 + 4 * ll);
    float4 p1 = *(const float4*)(ep + (size_t)x_s[1] * G4 + 4 * ll);

    for (int t = 0; t < len; t++) {
        float4 cur = p0;
        p0 = p1;
        int nt = (t + 2 < TMAX) ? t + 2 : TMAX - 1;
        p1 = *(const float4*)(ep + (size_t)x_s[nt] * G4 + 4 * ll);

        float gi = cur.x, gf = cur.y, gc = cur.z, go = cur.w;
#pragma unroll
        for (int k4 = 0; k4 < 13; k4++) {
            float4 h4 = *(const float4*)&h_s[4 * k4];   // broadcast read
            gi = fmaf(h4.x, rwi[k4].x, fmaf(h4.y, rwi[k4].y,
                 fmaf(h4.z, rwi[k4].z, fmaf(h4.w, rwi[k4].w, gi))));
            gf = fmaf(h4.x, rwf[k4].x, fmaf(h4.y, rwf[k4].y,
                 fmaf(h4.z, rwf[k4].z, fmaf(h4.w, rwf[k4].w, gf))));
            gc = fmaf(h4.x, rwg[k4].x, fmaf(h4.y, rwg[k4].y,
                 fmaf(h4.z, rwg[k4].z, fmaf(h4.w, rwg[k4].w, gc))));
            go = fmaf(h4.x, rwo[k4].x, fmaf(h4.y, rwo[k4].y,
                 fmaf(h4.z, rwo[k4].z, fmaf(h4.w, rwo[k4].w, go))));
        }
        float si = 1.f / (1.f + __expf(-gi));
        float sf = 1.f / (1.f + __expf(-gf));
        float so = 1.f / (1.f + __expf(-go));
        float cn = fmaf(sf, c_reg, si * tanh_f(gc));
        c_reg = cn;
        float hn = so * tanh_f(cn);
        if (l < DH) h_s[l] = hn;   // same wave: program order, no barrier
    }

    // logits + softmax (lanes 0-3)
    if (l < OUTC) {
        float lg = b_out[l];
        const float* wo = w_out + l * DH;
#pragma unroll
        for (int k = 0; k < DH; k++) lg = fmaf(h_s[k], wo[k], lg);
        red[l] = lg;
    }
    if (l < OUTC) {
        float m = fmaxf(fmaxf(red[0], red[1]), fmaxf(red[2], red[3]));
        float s = 0.f;
#pragma unroll
        for (int j = 0; j < OUTC; j++) s += __expf(red[j] - m);
        out[b * OUTC + l] = __expf(red[l] - m) / s;
    }
}

// ---------------------------------------------------------------------------
extern "C" void kernel_launch(void* const* d_in, const int* in_sizes, int n_in,
                              void* d_out, int out_size, void* d_ws, size_t ws_size,
                              hipStream_t stream) {
    const int*   x     = (const int*)d_in[0];
    const int*   lengs = (const int*)d_in[1];
    const float* emb   = (const float*)d_in[2];
    const float* w_ih  = (const float*)d_in[3];
    const float* w_hh  = (const float*)d_in[4];
    const float* b_ih  = (const float*)d_in[5];
    const float* b_hh  = (const float*)d_in[6];
    const float* w_out = (const float*)d_in[7];
    const float* b_out = (const float*)d_in[8];
    float* out = (float*)d_out;

    float* emb_proj = (float*)d_ws;                       // 40 MB
    float* w_T      = emb_proj + (size_t)VOCAB * G4;      // +240 KB

    hipLaunchKernelGGL(transpose_wih, dim3((G4 * DW + 255) / 256), dim3(256),
                       0, stream, w_ih, w_T);
    hipLaunchKernelGGL(proj_kernel, dim3(VOCAB / 100), dim3(256), 0, stream,
                       emb, w_T, b_ih, b_hh, emb_proj);
    hipLaunchKernelGGL(lstm_kernel, dim3(BATCH), dim3(64), 0, stream,
                       x, lengs, emb_proj, w_hh, w_out, b_out, out);
}